// Round 15
// baseline (395.738 us; speedup 1.0000x reference)
//
#include <hip/hip_runtime.h>
#include <hip/hip_cooperative_groups.h>

namespace cg = cooperative_groups;

// B=4, S=2048, D=E=1024, DIM=64 -> scale 0.125
// softmax quirk: normalized over the QUERY axis:
//   attn[b,q,k] = exp(s[b,q,k] - m[b,k]) / sum_q' exp(s[b,q',k] - m[b,k])
//
// R15:
//  * transpose-free algebra: W2T = Wk·Wq^T, Wvot = Wo^T·Wv^T (native NT, normal
//    stores via fast template); VWoT = NT(Wvot, v16) (R4/R5-verified form) —
//    EPI-4 scattered writes eliminated; proj = one flat 1024-block dispatch.
//  * cooperative scores+softmax (grid 16x16x4 = 1024 = 4/CU): partial column
//    stats via AGENT-scope atomics (G16) -> grid.sync -> normalized attn
//    written from live fp32 acc. Host checks coop-launch error and falls back
//    to the verified split path (scores+stats / stats2 / norm).

typedef _Float16 f16;
typedef _Float16 f16x8 __attribute__((ext_vector_type(8)));
typedef float f32x4 __attribute__((ext_vector_type(4)));

__device__ __forceinline__ void gl_lds16(const void* g, void* l) {
  __builtin_amdgcn_global_load_lds(
      (const __attribute__((address_space(1))) void*)(uintptr_t)g,
      (__attribute__((address_space(3))) void*)(uint32_t)(uintptr_t)l, 16, 0, 0);
}

// bijective XCD-chunked swizzle (m204)
__device__ __forceinline__ int xcd_swz(int F, int nwg) {
  int q = nwg >> 3, r = nwg & 7;
  int xcd = F & 7, idx = F >> 3;
  return (xcd < r ? xcd * (q + 1) : r * (q + 1) + (xcd - r) * q) + idx;
}

// C[M,N] = scale * A[M,K]*B[N,K]^T  (NT, fp16 operands, fp32 accum)
// EPI: 0 = fp32 C; 2 = fp16 C.  STATS: fused per-block column (max,sumexp).
// SWZ: XCD-chunked block swizzle.
template <int EPI, int STATS, int SWZ>
__global__ __launch_bounds__(256) void gemm16(
    const f16* __restrict__ Ag, const f16* __restrict__ Bg,
    float* __restrict__ Cf, f16* __restrict__ Ch,
    float* __restrict__ pm, float* __restrict__ pl,
    int K, int ldA, int ldB, int ldC, long sA, long sB, long sC, float scale) {
  __shared__ f16 sA_[128 * 64];
  __shared__ f16 sB_[128 * 64];

  const int tid = threadIdx.x;
  const int lane = tid & 63;
  const int wave = tid >> 6;
  int bx, by;
  long bz;
  if constexpr (SWZ) {
    const int gx = gridDim.x, gy = gridDim.y;
    const int nwg = gx * gy * gridDim.z;
    int F = blockIdx.x + gx * (blockIdx.y + gy * blockIdx.z);
    int wg = xcd_swz(F, nwg);
    bx = wg % gx;
    by = (wg / gx) % gy;
    bz = wg / (gx * gy);
  } else {
    bx = blockIdx.x;
    by = blockIdx.y;
    bz = blockIdx.z;
  }

  const int tM = by * 128;
  const int tN = bx * 128;
  const int wr = (wave >> 1) * 64;
  const int wc = (wave & 1) * 64;
  const int r16 = lane & 15;
  const int q4 = lane >> 4;

  const f16* Abase = Ag + bz * sA;
  const f16* Bbase = Bg + bz * sB;

  f32x4 acc[4][4] = {};

  for (int kt = 0; kt < K; kt += 64) {
#pragma unroll
    for (int it = 0; it < 4; ++it) {
      int row = it * 32 + (tid >> 3);
      int s = tid & 7;
      int gcol = kt + ((s ^ (row & 7)) << 3);
      int lo = row * 64 + s * 8;
      gl_lds16(Abase + (long)(tM + row) * ldA + gcol, sA_ + lo);
      gl_lds16(Bbase + (long)(tN + row) * ldB + gcol, sB_ + lo);
    }
    __syncthreads();
#pragma unroll
    for (int kk = 0; kk < 2; ++kk) {
      f16x8 ah[4], bh[4];
#pragma unroll
      for (int m = 0; m < 4; ++m) {
        int ar = wr + m * 16 + r16;
        ah[m] = *(const f16x8*)(sA_ + ar * 64 + (((kk * 4 + q4) ^ (ar & 7)) << 3));
      }
#pragma unroll
      for (int n = 0; n < 4; ++n) {
        int br = wc + n * 16 + r16;
        bh[n] = *(const f16x8*)(sB_ + br * 64 + (((kk * 4 + q4) ^ (br & 7)) << 3));
      }
#pragma unroll
      for (int m = 0; m < 4; ++m)
#pragma unroll
        for (int n = 0; n < 4; ++n)
          acc[m][n] = __builtin_amdgcn_mfma_f32_16x16x32_f16(ah[m], bh[n], acc[m][n], 0, 0, 0);
    }
    __syncthreads();
  }

#pragma unroll
  for (int m = 0; m < 4; ++m)
#pragma unroll
    for (int n = 0; n < 4; ++n)
#pragma unroll
      for (int j = 0; j < 4; ++j) {
        int rr = tM + wr + m * 16 + q4 * 4 + j;
        int cc = tN + wc + n * 16 + r16;
        float v = acc[m][n][j] * scale;
        if constexpr (EPI == 0)
          Cf[bz * sC + (long)rr * ldC + cc] = v;
        else
          Ch[bz * sC + (long)rr * ldC + cc] = (f16)v;
      }

  if constexpr (STATS) {
    float* mbuf = (float*)sA_;  // [2][128]
    float* lbuf = mbuf + 256;
    const int wrIdx = wave >> 1, c0 = wc;
#pragma unroll
    for (int n = 0; n < 4; ++n) {
      float mt = -1e30f;
#pragma unroll
      for (int m = 0; m < 4; ++m)
#pragma unroll
        for (int j = 0; j < 4; ++j) mt = fmaxf(mt, acc[m][n][j] * scale);
      float lt = 0.f;
#pragma unroll
      for (int m = 0; m < 4; ++m)
#pragma unroll
        for (int j = 0; j < 4; ++j) lt += __expf(acc[m][n][j] * scale - mt);
#pragma unroll
      for (int d = 16; d <= 32; d <<= 1) {
        float mo = __shfl_xor(mt, d);
        float lo = __shfl_xor(lt, d);
        float mn = fmaxf(mt, mo);
        lt = lt * __expf(mt - mn) + lo * __expf(mo - mn);
        mt = mn;
      }
      if (q4 == 0) {
        int c = c0 + n * 16 + r16;
        mbuf[wrIdx * 128 + c] = mt;
        lbuf[wrIdx * 128 + c] = lt;
      }
    }
    __syncthreads();
    if (tid < 128) {
      float m0 = mbuf[tid], m1 = mbuf[128 + tid];
      float l0 = lbuf[tid], l1 = lbuf[128 + tid];
      float mn = fmaxf(m0, m1);
      float ln = l0 * __expf(m0 - mn) + l1 * __expf(m1 - mn);
      long idx = (bz * 16 + (tM >> 7)) * 2048 + tN + tid;
      pm[idx] = mn;
      pl[idx] = ln;
    }
  }
}

// flat-grid dual-geometry projection (all normal coalesced stores):
// f <  512: Th[8192][1024]   = NT(q16, W2T)       (tiles 64x8)
// f >= 512: VWoT[b][1024][2048] = NT(Wvot, v16[b]) (tiles 8x16, b = (f-512)/128)
__global__ __launch_bounds__(256) void gemm_proj(
    const f16* __restrict__ q16, const f16* __restrict__ W2T, f16* __restrict__ Th,
    const f16* __restrict__ Wvot, const f16* __restrict__ v16, f16* __restrict__ VWoT) {
  __shared__ f16 sA_[128 * 64];
  __shared__ f16 sB_[128 * 64];
  const int tid = threadIdx.x;
  const int lane = tid & 63;
  const int wave = tid >> 6;

  const f16* Abase;
  const f16* Bbase;
  f16* Cbase;
  int tM, tN, ldC;
  int f = blockIdx.x;
  if (f < 512) {
    Abase = q16; Bbase = W2T; Cbase = Th;
    tM = (f >> 3) * 128; tN = (f & 7) * 128; ldC = 1024;
  } else {
    int g = f - 512, bz = g >> 7, t = g & 127;
    Abase = Wvot;
    Bbase = v16 + (long)bz * 2097152;
    Cbase = VWoT + (long)bz * 2097152;
    tM = (t >> 4) * 128; tN = (t & 15) * 128; ldC = 2048;
  }

  const int wr = (wave >> 1) * 64;
  const int wc = (wave & 1) * 64;
  const int r16 = lane & 15;
  const int q4 = lane >> 4;

  f32x4 acc[4][4] = {};

  for (int kt = 0; kt < 1024; kt += 64) {
#pragma unroll
    for (int it = 0; it < 4; ++it) {
      int row = it * 32 + (tid >> 3);
      int s = tid & 7;
      int gcol = kt + ((s ^ (row & 7)) << 3);
      int lo = row * 64 + s * 8;
      gl_lds16(Abase + (long)(tM + row) * 1024 + gcol, sA_ + lo);
      gl_lds16(Bbase + (long)(tN + row) * 1024 + gcol, sB_ + lo);
    }
    __syncthreads();
#pragma unroll
    for (int kk = 0; kk < 2; ++kk) {
      f16x8 ah[4], bh[4];
#pragma unroll
      for (int m = 0; m < 4; ++m) {
        int ar = wr + m * 16 + r16;
        ah[m] = *(const f16x8*)(sA_ + ar * 64 + (((kk * 4 + q4) ^ (ar & 7)) << 3));
      }
#pragma unroll
      for (int n = 0; n < 4; ++n) {
        int br = wc + n * 16 + r16;
        bh[n] = *(const f16x8*)(sB_ + br * 64 + (((kk * 4 + q4) ^ (br & 7)) << 3));
      }
#pragma unroll
      for (int m = 0; m < 4; ++m)
#pragma unroll
        for (int n = 0; n < 4; ++n)
          acc[m][n] = __builtin_amdgcn_mfma_f32_16x16x32_f16(ah[m], bh[n], acc[m][n], 0, 0, 0);
    }
    __syncthreads();
  }

#pragma unroll
  for (int m = 0; m < 4; ++m)
#pragma unroll
    for (int n = 0; n < 4; ++n)
#pragma unroll
      for (int j = 0; j < 4; ++j) {
        int rr = tM + wr + m * 16 + q4 * 4 + j;
        int cc = tN + wc + n * 16 + r16;
        Cbase[(long)rr * ldC + cc] = (f16)acc[m][n][j];
      }
}

// Cooperative scores+softmax: attn = exp(0.125*T·key^T - m[col]) * (1/l[col]).
// Cross-block stats via AGENT-scope atomics + grid.sync (G16).
__global__ __launch_bounds__(256, 4) void gemm_scores(
    const f16* __restrict__ Ag, const f16* __restrict__ Bg,
    f16* __restrict__ Ch, float* __restrict__ pm, float* __restrict__ pl) {
  __shared__ f16 sA_[128 * 64];
  __shared__ f16 sB_[128 * 64];

  const int tid = threadIdx.x;
  const int lane = tid & 63;
  const int wave = tid >> 6;
  const int gx = gridDim.x, gy = gridDim.y;
  const int nwg = gx * gy * gridDim.z;
  int F = blockIdx.x + gx * (blockIdx.y + gy * blockIdx.z);
  int wg = xcd_swz(F, nwg);
  const int bx = wg % gx;
  const int by = (wg / gx) % gy;
  const long bz = wg / (gx * gy);

  const int tM = by * 128;
  const int tN = bx * 128;
  const int wr = (wave >> 1) * 64;
  const int wc = (wave & 1) * 64;
  const int r16 = lane & 15;
  const int q4 = lane >> 4;

  const f16* Abase = Ag + bz * 2097152L;
  const f16* Bbase = Bg + bz * 2097152L;
  const float scale = 0.125f;

  f32x4 acc[4][4] = {};

  for (int kt = 0; kt < 1024; kt += 64) {
#pragma unroll
    for (int it = 0; it < 4; ++it) {
      int row = it * 32 + (tid >> 3);
      int s = tid & 7;
      int gcol = kt + ((s ^ (row & 7)) << 3);
      int lo = row * 64 + s * 8;
      gl_lds16(Abase + (long)(tM + row) * 1024 + gcol, sA_ + lo);
      gl_lds16(Bbase + (long)(tN + row) * 1024 + gcol, sB_ + lo);
    }
    __syncthreads();
#pragma unroll
    for (int kk = 0; kk < 2; ++kk) {
      f16x8 ah[4], bh[4];
#pragma unroll
      for (int m = 0; m < 4; ++m) {
        int ar = wr + m * 16 + r16;
        ah[m] = *(const f16x8*)(sA_ + ar * 64 + (((kk * 4 + q4) ^ (ar & 7)) << 3));
      }
#pragma unroll
      for (int n = 0; n < 4; ++n) {
        int br = wc + n * 16 + r16;
        bh[n] = *(const f16x8*)(sB_ + br * 64 + (((kk * 4 + q4) ^ (br & 7)) << 3));
      }
#pragma unroll
      for (int m = 0; m < 4; ++m)
#pragma unroll
        for (int n = 0; n < 4; ++n)
          acc[m][n] = __builtin_amdgcn_mfma_f32_16x16x32_f16(ah[m], bh[n], acc[m][n], 0, 0, 0);
    }
    __syncthreads();
  }

  // per-block column partials over this block's 128 q-rows
  {
    float* mbuf = (float*)sA_;  // [2][128]
    float* lbuf = mbuf + 256;
    const int wrIdx = wave >> 1, c0 = wc;
#pragma unroll
    for (int n = 0; n < 4; ++n) {
      float mt = -1e30f;
#pragma unroll
      for (int m = 0; m < 4; ++m)
#pragma unroll
        for (int j = 0; j < 4; ++j) mt = fmaxf(mt, acc[m][n][j] * scale);
      float lt = 0.f;
#pragma unroll
      for (int m = 0; m < 4; ++m)
#pragma unroll
        for (int j = 0; j < 4; ++j) lt += __expf(acc[m][n][j] * scale - mt);
#pragma unroll
      for (int d = 16; d <= 32; d <<= 1) {
        float mo = __shfl_xor(mt, d);
        float lo = __shfl_xor(lt, d);
        float mn = fmaxf(mt, mo);
        lt = lt * __expf(mt - mn) + lo * __expf(mo - mn);
        mt = mn;
      }
      if (q4 == 0) {
        int c = c0 + n * 16 + r16;
        mbuf[wrIdx * 128 + c] = mt;
        lbuf[wrIdx * 128 + c] = lt;
      }
    }
    __syncthreads();
    if (tid < 128) {
      float m0 = mbuf[tid], m1 = mbuf[128 + tid];
      float l0 = lbuf[tid], l1 = lbuf[128 + tid];
      float mn = fmaxf(m0, m1);
      float ln = l0 * __expf(m0 - mn) + l1 * __expf(m1 - mn);
      long idx = (bz * 16 + by) * 2048 + tN + tid;
      __hip_atomic_store(&pm[idx], mn, __ATOMIC_RELAXED, __HIP_MEMORY_SCOPE_AGENT);
      __hip_atomic_store(&pl[idx], ln, __ATOMIC_RELAXED, __HIP_MEMORY_SCOPE_AGENT);
    }
  }

  __threadfence();
  cg::this_grid().sync();

  // rebuild final per-column (m, 1/l) for this block's 128 columns
  float* mfin = (float*)sA_;  // [128]
  float* rfin = mfin + 128;   // [128]
  if (tid < 128) {
    float vm[16], vl[16];
    const float* pmb = pm + bz * 16 * 2048 + tN + tid;
    const float* plb = pl + bz * 16 * 2048 + tN + tid;
#pragma unroll
    for (int qc = 0; qc < 16; ++qc) {
      vm[qc] = __hip_atomic_load(&pmb[qc * 2048], __ATOMIC_RELAXED, __HIP_MEMORY_SCOPE_AGENT);
      vl[qc] = __hip_atomic_load(&plb[qc * 2048], __ATOMIC_RELAXED, __HIP_MEMORY_SCOPE_AGENT);
    }
    float m = -1e30f;
#pragma unroll
    for (int qc = 0; qc < 16; ++qc) m = fmaxf(m, vm[qc]);
    float l = 0.f;
#pragma unroll
    for (int qc = 0; qc < 16; ++qc) l += vl[qc] * __expf(vm[qc] - m);
    mfin[tid] = m;
    rfin[tid] = 1.f / l;
  }
  __syncthreads();

  // write normalized attn fp16 directly from live fp32 acc
#pragma unroll
  for (int m = 0; m < 4; ++m)
#pragma unroll
    for (int n = 0; n < 4; ++n) {
      int ccl = wc + n * 16 + r16;
      float mm = mfin[ccl];
      float rl = rfin[ccl];
#pragma unroll
      for (int j = 0; j < 4; ++j) {
        int rr = tM + wr + m * 16 + q4 * 4 + j;
        Ch[bz * 4194304L + (long)rr * 2048 + tN + ccl] =
            (f16)(__expf(acc[m][n][j] * scale - mm) * rl);
      }
    }
}

// fused fp32 -> fp16 conversion
__global__ __launch_bounds__(256) void convert6(
    const float* __restrict__ i0, const float* __restrict__ i1,
    const float* __restrict__ i2, const float* __restrict__ i3,
    const float* __restrict__ i4, const float* __restrict__ i5,
    f16* __restrict__ o0, f16* __restrict__ o1, f16* __restrict__ o2,
    f16* __restrict__ o3, f16* __restrict__ o4, f16* __restrict__ o5,
    long nbig, long nsmall) {
  const int z = blockIdx.z;
  const float* in;
  f16* hi;
  long n;
  switch (z) {
    case 0: in = i0; hi = o0; n = nbig; break;
    case 1: in = i1; hi = o1; n = nbig; break;
    case 2: in = i2; hi = o2; n = nbig; break;
    case 3: in = i3; hi = o3; n = nsmall; break;
    case 4: in = i4; hi = o4; n = nsmall; break;
    default: in = i5; hi = o5; n = nsmall; break;
  }
  long i = ((long)blockIdx.x * 256 + threadIdx.x) * 8;
  if (i >= n) return;
  float4 aa = *(const float4*)(in + i);
  float4 bb = *(const float4*)(in + i + 4);
  f16x8 h;
  h[0] = (f16)aa.x; h[1] = (f16)aa.y; h[2] = (f16)aa.z; h[3] = (f16)aa.w;
  h[4] = (f16)bb.x; h[5] = (f16)bb.y; h[6] = (f16)bb.z; h[7] = (f16)bb.w;
  *(f16x8*)(hi + i) = h;
}

// transpose + fp16 convert (Wo -> Wot)
__global__ void tconv(const float* __restrict__ in, f16* __restrict__ hi, int n) {
  __shared__ float t[32][33];
  int bx = blockIdx.x * 32, by = blockIdx.y * 32;
  int tx = threadIdx.x, ty = threadIdx.y;  // 32 x 8
  for (int i = 0; i < 32; i += 8) t[ty + i][tx] = in[(long)(by + ty + i) * n + bx + tx];
  __syncthreads();
  for (int i = 0; i < 32; i += 8)
    hi[(long)(bx + ty + i) * n + by + tx] = (f16)t[tx][ty + i];
}

// fallback: reduce 16 partials -> (m, 1/l) per column
__global__ void stats2(const float* __restrict__ pm, const float* __restrict__ pl,
                       float* __restrict__ mfo, float* __restrict__ rlo) {
  int c = blockIdx.x * 256 + threadIdx.x;  // b*2048 + k
  int b = c >> 11, k = c & 2047;
  float m = -1e30f;
  for (int qc = 0; qc < 16; ++qc) m = fmaxf(m, pm[(b * 16 + qc) * 2048 + k]);
  float l = 0.f;
  for (int qc = 0; qc < 16; ++qc)
    l += pl[(b * 16 + qc) * 2048 + k] * __expf(pm[(b * 16 + qc) * 2048 + k] - m);
  mfo[c] = m;
  rlo[c] = 1.f / l;
}

// fallback: in-place normalize
__global__ __launch_bounds__(256) void norm(f16* __restrict__ S16,
                                            const float* __restrict__ mf,
                                            const float* __restrict__ rl) {
  long row = blockIdx.x;  // b*2048 + q
  int b = (int)(row >> 11);
  f16* Sr = S16 + row * 2048;
  const float* mb = mf + ((long)b << 11);
  const float* rb = rl + ((long)b << 11);
  int c = threadIdx.x * 8;
  f16x8 v = *(f16x8*)(Sr + c);
  float4 m0 = *(const float4*)(mb + c);
  float4 m1 = *(const float4*)(mb + c + 4);
  float4 r0 = *(const float4*)(rb + c);
  float4 r1 = *(const float4*)(rb + c + 4);
  f16x8 o;
  o[0] = (f16)(__expf((float)v[0] - m0.x) * r0.x);
  o[1] = (f16)(__expf((float)v[1] - m0.y) * r0.y);
  o[2] = (f16)(__expf((float)v[2] - m0.z) * r0.z);
  o[3] = (f16)(__expf((float)v[3] - m0.w) * r0.w);
  o[4] = (f16)(__expf((float)v[4] - m1.x) * r1.x);
  o[5] = (f16)(__expf((float)v[5] - m1.y) * r1.y);
  o[6] = (f16)(__expf((float)v[6] - m1.z) * r1.z);
  o[7] = (f16)(__expf((float)v[7] - m1.w) * r1.w);
  *(f16x8*)(Sr + c) = o;
}

extern "C" void kernel_launch(void* const* d_in, const int* in_sizes, int n_in,
                              void* d_out, int out_size, void* d_ws, size_t ws_size,
                              hipStream_t stream) {
  const float* query = (const float*)d_in[0];
  const float* key   = (const float*)d_in[1];
  const float* value = (const float*)d_in[2];
  const float* Wq    = (const float*)d_in[3];
  const float* Wk    = (const float*)d_in[4];
  const float* Wv    = (const float*)d_in[5];
  const float* Wo    = (const float*)d_in[6];
  float* out = (float*)d_out;

  // arena (f16-element offsets), ~130 MB
  f16* h = (f16*)d_ws;
  const long E8 = 8388608L;  // 8192*1024
  const long E1 = 1048576L;  // 1024*1024
  f16* q16   = h;
  f16* v16   = h + E8;
  f16* k16   = h + 2 * E8;
  f16* Th    = h + 3 * E8;   // [8192][1024]
  f16* VWoT  = h + 4 * E8;   // [4][1024][2048]
  f16* WB    = h + 5 * E8;   // six E1 slots (fold A/B/C batches, stride E1):
  f16* Wk16  = WB;           //   fold A z0
  f16* Wot   = WB + E1;      //   fold A z1
  f16* Wq16  = WB + 2 * E1;  //   fold B z0
  f16* wv16  = WB + 3 * E1;  //   fold B z1
  f16* W2T   = WB + 4 * E1;  //   fold C z0
  f16* Wvot  = WB + 5 * E1;  //   fold C z1
  f16* S16   = WB + 6 * E1;  // [4][2048][2048] fp16 attn
  float* pm  = (float*)(S16 + 16777216L);  // [4][16][2048]
  float* pl  = pm + 131072;
  float* mf  = pl + 131072;  // fallback finals
  float* rl  = mf + 8192;
  (void)in_sizes; (void)n_in; (void)out_size; (void)ws_size;

  dim3 tb32(32, 8);
  tconv<<<dim3(32, 32), tb32, 0, stream>>>(Wo, Wot, 1024);

  // fused input conversions
  convert6<<<dim3(4096, 1, 6), 256, 0, stream>>>(
      query, key, value, Wq, Wk, Wv, q16, k16, v16, Wq16, Wk16, wv16, E8, E1);

  // weight folds (transpose-free NT): z0 W2T = Wk·Wq^T, z1 Wvot = Wo^T·Wv^T
  gemm16<2, 0, 0><<<dim3(8, 8, 2), 256, 0, stream>>>(
      Wk16, Wq16, nullptr, W2T, nullptr, nullptr,
      1024, 1024, 1024, 1024, E1, E1, E1, 1.f);

  // projections, flat 1024-block dispatch: Th = q16@W2, VWoT[b] = NT(Wvot, v16[b])
  gemm_proj<<<dim3(1024), 256, 0, stream>>>(q16, W2T, Th, Wvot, v16, VWoT);

  // cooperative scores + softmax-over-q (error-checked, with fallback)
  {
    const f16* a = Th;
    const f16* b = k16;
    f16* c = S16;
    float* pma = pm;
    float* pla = pl;
    void* args[] = {&a, &b, &c, &pma, &pla};
    hipError_t ce = hipLaunchCooperativeKernel((const void*)gemm_scores,
                                               dim3(16, 16, 4), dim3(256, 1, 1),
                                               args, 0, stream);
    if (ce != hipSuccess) {
      (void)hipGetLastError();  // clear sticky error
      gemm16<2, 1, 1><<<dim3(16, 16, 4), 256, 0, stream>>>(
          Th, k16, nullptr, S16, pm, pl,
          1024, 1024, 1024, 2048, 2097152L, 2097152L, 4194304L, 0.125f);
      stats2<<<32, 256, 0, stream>>>(pm, pl, mf, rl);
      norm<<<8192, 256, 0, stream>>>(S16, mf, rl);
    }
  }

  // out = attn @ VWo per batch (M=2048, N=1024, K=2048), fp32 out
  gemm16<0, 0, 1><<<dim3(8, 16, 4), 256, 0, stream>>>(
      S16, VWoT, out, nullptr, nullptr, nullptr,
      2048, 2048, 2048, 1024, 4194304L, 2097152L, 2097152L, 1.f);
}

// Round 16
// 206.625 us; speedup vs baseline: 1.9152x; 1.9152x over previous
//
#include <hip/hip_runtime.h>

// B=4, S=2048, D=E=1024, DIM=64 -> scale 0.125
// softmax quirk: normalized over the QUERY axis:
//   attn[b,q,k] = exp(s[b,q,k] - m[b,k]) / sum_q' exp(s[b,q',k] - m[b,k])
//
// R16 = R13 verified split-softmax pipeline + R15 transpose-free algebra:
//   W2T = Wk·Wq^T, Wvot = Wo^T·Wv^T (native NT folds, normal stores)
//   flat 1024-block proj: Th = q16@W2 and VWoT[b] = NT(Wvot, v16[b]),
//   both with coalesced epilogues (replaces EPI-4 scatter writes).
//   scores (fused col-stats) -> stats2 -> norm -> final attn@VWo.
// (cooperative grid.sync path measured 234us @ MfmaUtil 5.7% in R15 - dead end)

typedef _Float16 f16;
typedef _Float16 f16x8 __attribute__((ext_vector_type(8)));
typedef float f32x4 __attribute__((ext_vector_type(4)));

__device__ __forceinline__ void gl_lds16(const void* g, void* l) {
  __builtin_amdgcn_global_load_lds(
      (const __attribute__((address_space(1))) void*)(uintptr_t)g,
      (__attribute__((address_space(3))) void*)(uint32_t)(uintptr_t)l, 16, 0, 0);
}

// bijective XCD-chunked swizzle (m204)
__device__ __forceinline__ int xcd_swz(int F, int nwg) {
  int q = nwg >> 3, r = nwg & 7;
  int xcd = F & 7, idx = F >> 3;
  return (xcd < r ? xcd * (q + 1) : r * (q + 1) + (xcd - r) * q) + idx;
}

// C[M,N] = scale * A[M,K]*B[N,K]^T  (NT, fp16 operands, fp32 accum)
// EPI: 0 = fp32 C; 2 = fp16 C.  STATS: fused per-block column (max,sumexp).
// SWZ: XCD-chunked block swizzle.
template <int EPI, int STATS, int SWZ>
__global__ __launch_bounds__(256) void gemm16(
    const f16* __restrict__ Ag, const f16* __restrict__ Bg,
    float* __restrict__ Cf, f16* __restrict__ Ch,
    float* __restrict__ pm, float* __restrict__ pl,
    int K, int ldA, int ldB, int ldC, long sA, long sB, long sC, float scale) {
  __shared__ f16 sA_[128 * 64];
  __shared__ f16 sB_[128 * 64];

  const int tid = threadIdx.x;
  const int lane = tid & 63;
  const int wave = tid >> 6;
  int bx, by;
  long bz;
  if constexpr (SWZ) {
    const int gx = gridDim.x, gy = gridDim.y;
    const int nwg = gx * gy * gridDim.z;
    int F = blockIdx.x + gx * (blockIdx.y + gy * blockIdx.z);
    int wg = xcd_swz(F, nwg);
    bx = wg % gx;
    by = (wg / gx) % gy;
    bz = wg / (gx * gy);
  } else {
    bx = blockIdx.x;
    by = blockIdx.y;
    bz = blockIdx.z;
  }

  const int tM = by * 128;
  const int tN = bx * 128;
  const int wr = (wave >> 1) * 64;
  const int wc = (wave & 1) * 64;
  const int r16 = lane & 15;
  const int q4 = lane >> 4;

  const f16* Abase = Ag + bz * sA;
  const f16* Bbase = Bg + bz * sB;

  f32x4 acc[4][4] = {};

  for (int kt = 0; kt < K; kt += 64) {
#pragma unroll
    for (int it = 0; it < 4; ++it) {
      int row = it * 32 + (tid >> 3);
      int s = tid & 7;
      int gcol = kt + ((s ^ (row & 7)) << 3);
      int lo = row * 64 + s * 8;
      gl_lds16(Abase + (long)(tM + row) * ldA + gcol, sA_ + lo);
      gl_lds16(Bbase + (long)(tN + row) * ldB + gcol, sB_ + lo);
    }
    __syncthreads();
#pragma unroll
    for (int kk = 0; kk < 2; ++kk) {
      f16x8 ah[4], bh[4];
#pragma unroll
      for (int m = 0; m < 4; ++m) {
        int ar = wr + m * 16 + r16;
        ah[m] = *(const f16x8*)(sA_ + ar * 64 + (((kk * 4 + q4) ^ (ar & 7)) << 3));
      }
#pragma unroll
      for (int n = 0; n < 4; ++n) {
        int br = wc + n * 16 + r16;
        bh[n] = *(const f16x8*)(sB_ + br * 64 + (((kk * 4 + q4) ^ (br & 7)) << 3));
      }
#pragma unroll
      for (int m = 0; m < 4; ++m)
#pragma unroll
        for (int n = 0; n < 4; ++n)
          acc[m][n] = __builtin_amdgcn_mfma_f32_16x16x32_f16(ah[m], bh[n], acc[m][n], 0, 0, 0);
    }
    __syncthreads();
  }

#pragma unroll
  for (int m = 0; m < 4; ++m)
#pragma unroll
    for (int n = 0; n < 4; ++n)
#pragma unroll
      for (int j = 0; j < 4; ++j) {
        int rr = tM + wr + m * 16 + q4 * 4 + j;
        int cc = tN + wc + n * 16 + r16;
        float v = acc[m][n][j] * scale;
        if constexpr (EPI == 0)
          Cf[bz * sC + (long)rr * ldC + cc] = v;
        else
          Ch[bz * sC + (long)rr * ldC + cc] = (f16)v;
      }

  if constexpr (STATS) {
    float* mbuf = (float*)sA_;  // [2][128]
    float* lbuf = mbuf + 256;
    const int wrIdx = wave >> 1, c0 = wc;
#pragma unroll
    for (int n = 0; n < 4; ++n) {
      float mt = -1e30f;
#pragma unroll
      for (int m = 0; m < 4; ++m)
#pragma unroll
        for (int j = 0; j < 4; ++j) mt = fmaxf(mt, acc[m][n][j] * scale);
      float lt = 0.f;
#pragma unroll
      for (int m = 0; m < 4; ++m)
#pragma unroll
        for (int j = 0; j < 4; ++j) lt += __expf(acc[m][n][j] * scale - mt);
#pragma unroll
      for (int d = 16; d <= 32; d <<= 1) {
        float mo = __shfl_xor(mt, d);
        float lo = __shfl_xor(lt, d);
        float mn = fmaxf(mt, mo);
        lt = lt * __expf(mt - mn) + lo * __expf(mo - mn);
        mt = mn;
      }
      if (q4 == 0) {
        int c = c0 + n * 16 + r16;
        mbuf[wrIdx * 128 + c] = mt;
        lbuf[wrIdx * 128 + c] = lt;
      }
    }
    __syncthreads();
    if (tid < 128) {
      float m0 = mbuf[tid], m1 = mbuf[128 + tid];
      float l0 = lbuf[tid], l1 = lbuf[128 + tid];
      float mn = fmaxf(m0, m1);
      float ln = l0 * __expf(m0 - mn) + l1 * __expf(m1 - mn);
      long idx = (bz * 16 + (tM >> 7)) * 2048 + tN + tid;
      pm[idx] = mn;
      pl[idx] = ln;
    }
  }
}

// flat-grid dual-geometry projection (all normal coalesced stores):
// f <  512: Th[8192][1024]     = NT(q16, W2T)      (tiles 64x8)
// f >= 512: VWoT[b][1024][2048] = NT(Wvot, v16[b])  (tiles 8x16, b=(f-512)/128)
__global__ __launch_bounds__(256) void gemm_proj(
    const f16* __restrict__ q16, const f16* __restrict__ W2T, f16* __restrict__ Th,
    const f16* __restrict__ Wvot, const f16* __restrict__ v16, f16* __restrict__ VWoT) {
  __shared__ f16 sA_[128 * 64];
  __shared__ f16 sB_[128 * 64];
  const int tid = threadIdx.x;
  const int lane = tid & 63;
  const int wave = tid >> 6;

  const f16* Abase;
  const f16* Bbase;
  f16* Cbase;
  int tM, tN, ldC;
  int f = blockIdx.x;
  if (f < 512) {
    Abase = q16; Bbase = W2T; Cbase = Th;
    tM = (f >> 3) * 128; tN = (f & 7) * 128; ldC = 1024;
  } else {
    int g = f - 512, bz = g >> 7, t = g & 127;
    Abase = Wvot;
    Bbase = v16 + (long)bz * 2097152;
    Cbase = VWoT + (long)bz * 2097152;
    tM = (t >> 4) * 128; tN = (t & 15) * 128; ldC = 2048;
  }

  const int wr = (wave >> 1) * 64;
  const int wc = (wave & 1) * 64;
  const int r16 = lane & 15;
  const int q4 = lane >> 4;

  f32x4 acc[4][4] = {};

  for (int kt = 0; kt < 1024; kt += 64) {
#pragma unroll
    for (int it = 0; it < 4; ++it) {
      int row = it * 32 + (tid >> 3);
      int s = tid & 7;
      int gcol = kt + ((s ^ (row & 7)) << 3);
      int lo = row * 64 + s * 8;
      gl_lds16(Abase + (long)(tM + row) * 1024 + gcol, sA_ + lo);
      gl_lds16(Bbase + (long)(tN + row) * 1024 + gcol, sB_ + lo);
    }
    __syncthreads();
#pragma unroll
    for (int kk = 0; kk < 2; ++kk) {
      f16x8 ah[4], bh[4];
#pragma unroll
      for (int m = 0; m < 4; ++m) {
        int ar = wr + m * 16 + r16;
        ah[m] = *(const f16x8*)(sA_ + ar * 64 + (((kk * 4 + q4) ^ (ar & 7)) << 3));
      }
#pragma unroll
      for (int n = 0; n < 4; ++n) {
        int br = wc + n * 16 + r16;
        bh[n] = *(const f16x8*)(sB_ + br * 64 + (((kk * 4 + q4) ^ (br & 7)) << 3));
      }
#pragma unroll
      for (int m = 0; m < 4; ++m)
#pragma unroll
        for (int n = 0; n < 4; ++n)
          acc[m][n] = __builtin_amdgcn_mfma_f32_16x16x32_f16(ah[m], bh[n], acc[m][n], 0, 0, 0);
    }
    __syncthreads();
  }

#pragma unroll
  for (int m = 0; m < 4; ++m)
#pragma unroll
    for (int n = 0; n < 4; ++n)
#pragma unroll
      for (int j = 0; j < 4; ++j) {
        int rr = tM + wr + m * 16 + q4 * 4 + j;
        int cc = tN + wc + n * 16 + r16;
        Cbase[(long)rr * ldC + cc] = (f16)acc[m][n][j];
      }
}

// fused fp32 -> fp16 conversion
__global__ __launch_bounds__(256) void convert6(
    const float* __restrict__ i0, const float* __restrict__ i1,
    const float* __restrict__ i2, const float* __restrict__ i3,
    const float* __restrict__ i4, const float* __restrict__ i5,
    f16* __restrict__ o0, f16* __restrict__ o1, f16* __restrict__ o2,
    f16* __restrict__ o3, f16* __restrict__ o4, f16* __restrict__ o5,
    long nbig, long nsmall) {
  const int z = blockIdx.z;
  const float* in;
  f16* hi;
  long n;
  switch (z) {
    case 0: in = i0; hi = o0; n = nbig; break;
    case 1: in = i1; hi = o1; n = nbig; break;
    case 2: in = i2; hi = o2; n = nbig; break;
    case 3: in = i3; hi = o3; n = nsmall; break;
    case 4: in = i4; hi = o4; n = nsmall; break;
    default: in = i5; hi = o5; n = nsmall; break;
  }
  long i = ((long)blockIdx.x * 256 + threadIdx.x) * 8;
  if (i >= n) return;
  float4 aa = *(const float4*)(in + i);
  float4 bb = *(const float4*)(in + i + 4);
  f16x8 h;
  h[0] = (f16)aa.x; h[1] = (f16)aa.y; h[2] = (f16)aa.z; h[3] = (f16)aa.w;
  h[4] = (f16)bb.x; h[5] = (f16)bb.y; h[6] = (f16)bb.z; h[7] = (f16)bb.w;
  *(f16x8*)(hi + i) = h;
}

// transpose + fp16 convert (Wo -> Wot)
__global__ void tconv(const float* __restrict__ in, f16* __restrict__ hi, int n) {
  __shared__ float t[32][33];
  int bx = blockIdx.x * 32, by = blockIdx.y * 32;
  int tx = threadIdx.x, ty = threadIdx.y;  // 32 x 8
  for (int i = 0; i < 32; i += 8) t[ty + i][tx] = in[(long)(by + ty + i) * n + bx + tx];
  __syncthreads();
  for (int i = 0; i < 32; i += 8)
    hi[(long)(bx + ty + i) * n + by + tx] = (f16)t[tx][ty + i];
}

// reduce 16 per-block-row partials -> final m, 1/l per column
__global__ void stats2(const float* __restrict__ pm, const float* __restrict__ pl,
                       float* __restrict__ mfo, float* __restrict__ rlo) {
  int c = blockIdx.x * 256 + threadIdx.x;  // b*2048 + k
  int b = c >> 11, k = c & 2047;
  float m = -1e30f;
  for (int qc = 0; qc < 16; ++qc) m = fmaxf(m, pm[(b * 16 + qc) * 2048 + k]);
  float l = 0.f;
  for (int qc = 0; qc < 16; ++qc)
    l += pl[(b * 16 + qc) * 2048 + k] * __expf(pm[(b * 16 + qc) * 2048 + k] - m);
  mfo[c] = m;
  rlo[c] = 1.f / l;
}

// in-place: S16 <- exp(S16 - m[col]) * rl[col]   (fp16)
__global__ __launch_bounds__(256) void norm(f16* __restrict__ S16,
                                            const float* __restrict__ mf,
                                            const float* __restrict__ rl) {
  long row = blockIdx.x;  // b*2048 + q
  int b = (int)(row >> 11);
  f16* Sr = S16 + row * 2048;
  const float* mb = mf + ((long)b << 11);
  const float* rb = rl + ((long)b << 11);
  int c = threadIdx.x * 8;
  f16x8 v = *(f16x8*)(Sr + c);
  float4 m0 = *(const float4*)(mb + c);
  float4 m1 = *(const float4*)(mb + c + 4);
  float4 r0 = *(const float4*)(rb + c);
  float4 r1 = *(const float4*)(rb + c + 4);
  f16x8 o;
  o[0] = (f16)(__expf((float)v[0] - m0.x) * r0.x);
  o[1] = (f16)(__expf((float)v[1] - m0.y) * r0.y);
  o[2] = (f16)(__expf((float)v[2] - m0.z) * r0.z);
  o[3] = (f16)(__expf((float)v[3] - m0.w) * r0.w);
  o[4] = (f16)(__expf((float)v[4] - m1.x) * r1.x);
  o[5] = (f16)(__expf((float)v[5] - m1.y) * r1.y);
  o[6] = (f16)(__expf((float)v[6] - m1.z) * r1.z);
  o[7] = (f16)(__expf((float)v[7] - m1.w) * r1.w);
  *(f16x8*)(Sr + c) = o;
}

extern "C" void kernel_launch(void* const* d_in, const int* in_sizes, int n_in,
                              void* d_out, int out_size, void* d_ws, size_t ws_size,
                              hipStream_t stream) {
  const float* query = (const float*)d_in[0];
  const float* key   = (const float*)d_in[1];
  const float* value = (const float*)d_in[2];
  const float* Wq    = (const float*)d_in[3];
  const float* Wk    = (const float*)d_in[4];
  const float* Wv    = (const float*)d_in[5];
  const float* Wo    = (const float*)d_in[6];
  float* out = (float*)d_out;

  // arena (f16-element offsets), ~130 MB
  f16* h = (f16*)d_ws;
  const long E8 = 8388608L;  // 8192*1024
  const long E1 = 1048576L;  // 1024*1024
  f16* q16   = h;
  f16* v16   = h + E8;
  f16* k16   = h + 2 * E8;
  f16* Th    = h + 3 * E8;   // [8192][1024]
  f16* VWoT  = h + 4 * E8;   // [4][1024][2048]
  f16* WB    = h + 5 * E8;   // six E1 slots (fold A/B/C batches, stride E1):
  f16* Wk16  = WB;           //   fold A z0
  f16* Wot   = WB + E1;      //   fold A z1
  f16* Wq16  = WB + 2 * E1;  //   fold B z0
  f16* wv16  = WB + 3 * E1;  //   fold B z1
  f16* W2T   = WB + 4 * E1;  //   fold C z0
  f16* Wvot  = WB + 5 * E1;  //   fold C z1
  f16* S16   = WB + 6 * E1;  // [4][2048][2048] fp16 scores -> attn (in place)
  float* pm  = (float*)(S16 + 16777216L);  // [4][16][2048]
  float* pl  = pm + 131072;
  float* mf  = pl + 131072;  // 8192
  float* rl  = mf + 8192;
  (void)in_sizes; (void)n_in; (void)out_size; (void)ws_size;

  dim3 tb32(32, 8);
  tconv<<<dim3(32, 32), tb32, 0, stream>>>(Wo, Wot, 1024);

  // fused input conversions (query, key, value, Wq, Wk, Wv)
  convert6<<<dim3(4096, 1, 6), 256, 0, stream>>>(
      query, key, value, Wq, Wk, Wv, q16, k16, v16, Wq16, Wk16, wv16, E8, E1);

  // weight folds (transpose-free NT): z0 W2T = Wk·Wq^T, z1 Wvot = Wo^T·Wv^T
  gemm16<2, 0, 0><<<dim3(8, 8, 2), 256, 0, stream>>>(
      Wk16, Wq16, nullptr, W2T, nullptr, nullptr,
      1024, 1024, 1024, 1024, E1, E1, E1, 1.f);

  // projections, flat 1024-block dispatch: Th = q16@W2, VWoT[b] = NT(Wvot, v16[b])
  gemm_proj<<<dim3(1024), 256, 0, stream>>>(q16, W2T, Th, Wvot, v16, VWoT);

  // scores = 0.125 * T key^T per batch, fp16 out + fused column stats
  gemm16<2, 1, 1><<<dim3(16, 16, 4), 256, 0, stream>>>(
      Th, k16, nullptr, S16, pm, pl,
      1024, 1024, 1024, 2048, 2097152L, 2097152L, 4194304L, 0.125f);

  // reduce partials, then normalize in place
  stats2<<<32, 256, 0, stream>>>(pm, pl, mf, rl);
  norm<<<8192, 256, 0, stream>>>(S16, mf, rl);

  // out = attn @ VWo per batch (M=2048, N=1024, K=2048), fp32 out
  gemm16<0, 0, 1><<<dim3(8, 16, 4), 256, 0, stream>>>(
      S16, VWoT, out, nullptr, nullptr, nullptr,
      2048, 2048, 2048, 1024, 4194304L, 2097152L, 2097152L, 1.f);
}